// Round 10
// baseline (19.718 us; speedup 1.0000x reference)
//
#include <hip/hip_runtime.h>

#define BB 8
#define SS 4096
#define DD 1024
#define TEMP 0.1f
#define PADV -100.0f
#define EPSV 1e-8f

// One block (1024 threads) per batch. Scan labels for compacted ranks, then
// scatter-build desc[j] = (pos_j, pos_{(j+1)%c}) directly (proven R9 variant).
// Pads (-1,-1) and both output chunks' -100 pads written by rank owners.
__global__ __launch_bounds__(1024) void compact_kernel(const int* __restrict__ labels,
                                                       int2* __restrict__ desc,
                                                       float* __restrict__ out_cos,
                                                       float* __restrict__ out_lab) {
    int b = blockIdx.x;
    int t = threadIdx.x;
    int lane = t & 63, wave = t >> 6;

    __shared__ int wsum[16];

    int4 v = ((const int4*)(labels + b * SS))[t];
    int vals[4] = {v.x, v.y, v.z, v.w};
    int mycnt = (vals[0] != -100) + (vals[1] != -100) + (vals[2] != -100) + (vals[3] != -100);

    int scan = mycnt;
#pragma unroll
    for (int off = 1; off < 64; off <<= 1) {
        int n = __shfl_up(scan, off, 64);
        if (lane >= off) scan += n;
    }
    if (lane == 63) wsum[wave] = scan;
    __syncthreads();

    int wbase = 0, c = 0;
#pragma unroll
    for (int w = 0; w < 16; ++w) {
        int s = wsum[w];
        wbase += (w < wave) ? s : 0;
        c += s;
    }
    int r = wbase + scan - mycnt;

    int2*  db = desc + (size_t)b * SS;
    float* lb = out_lab + b * SS;

#pragma unroll
    for (int i = 0; i < 4; ++i) {
        if (vals[i] != -100) {
            int p = 4 * t + i;
            lb[r] = (float)vals[i];
            db[r].x = p;
            int rp = (r == 0) ? (c - 1) : (r - 1);
            db[rp].y = p;
            ++r;
        }
    }
#pragma unroll
    for (int i = 0; i < 4; ++i) {
        int s = 4 * t + i;
        if (s >= c) {
            lb[s] = PADV;
            out_cos[b * SS + s] = PADV;
            db[s] = make_int2(-1, -1);
        }
    }
}

// One WAVE per 4 consecutive ranks: 5 vectors A..E loaded IN PARALLEL
// (1.25 loads/pair), 9-value butterfly, one aligned float4 store by lane 0.
// Positions: A = d[0].x, B..E = d[0..3].y (.y absorbs the cyclic wrap).
__global__ __launch_bounds__(256) void cos_kernel(const float* __restrict__ x,
                                                  const int2* __restrict__ desc,
                                                  float* __restrict__ out_cos) {
    int b    = blockIdx.y;
    int lane = threadIdx.x & 63;
    int wid  = threadIdx.x >> 6;
    int j0   = (blockIdx.x * 4 + wid) * 4;

    const int2* dbase = desc + (size_t)b * SS + j0;
    int4 d01 = *(const int4*)(dbase + 0);     // desc[j0], desc[j0+1]
    if (d01.x < 0) return;                    // wave-uniform: all 4 ranks pad
    int4 d23 = *(const int4*)(dbase + 2);     // desc[j0+2], desc[j0+3]

    bool v1 = (d01.z >= 0), v2 = (d23.x >= 0), v3 = (d23.z >= 0);
    int pA = d01.x;
    int pB = d01.y;
    int pC = v1 ? d01.w : pA;                 // fallbacks keep pointers valid
    int pD = v2 ? d23.y : pA;
    int pE = v3 ? d23.w : pA;

    const float* xb = x + (size_t)b * SS * DD + (size_t)lane * 4;
    const float* qa = xb + (size_t)pA * DD;
    const float* qb = xb + (size_t)pB * DD;
    const float* qc = xb + (size_t)pC * DD;
    const float* qd = xb + (size_t)pD * DD;
    const float* qe = xb + (size_t)pE * DD;

    float4 A[4], B[4], C[4], D[4], E[4];
#pragma unroll
    for (int q = 0; q < 4; ++q) {
        A[q] = *(const float4*)(qa + q * 256);
        B[q] = *(const float4*)(qb + q * 256);
        C[q] = *(const float4*)(qc + q * 256);
        D[q] = *(const float4*)(qd + q * 256);
        E[q] = *(const float4*)(qe + q * 256);
    }

    float na = 0.f, nb = 0.f, nc = 0.f, nd = 0.f, ne = 0.f;
    float dab = 0.f, dbc = 0.f, dcd = 0.f, dde = 0.f;
#pragma unroll
    for (int q = 0; q < 4; ++q) {
        na  += A[q].x*A[q].x + A[q].y*A[q].y + A[q].z*A[q].z + A[q].w*A[q].w;
        nb  += B[q].x*B[q].x + B[q].y*B[q].y + B[q].z*B[q].z + B[q].w*B[q].w;
        nc  += C[q].x*C[q].x + C[q].y*C[q].y + C[q].z*C[q].z + C[q].w*C[q].w;
        nd  += D[q].x*D[q].x + D[q].y*D[q].y + D[q].z*D[q].z + D[q].w*D[q].w;
        ne  += E[q].x*E[q].x + E[q].y*E[q].y + E[q].z*E[q].z + E[q].w*E[q].w;
        dab += A[q].x*B[q].x + A[q].y*B[q].y + A[q].z*B[q].z + A[q].w*B[q].w;
        dbc += B[q].x*C[q].x + B[q].y*C[q].y + B[q].z*C[q].z + B[q].w*C[q].w;
        dcd += C[q].x*D[q].x + C[q].y*D[q].y + C[q].z*D[q].z + C[q].w*D[q].w;
        dde += D[q].x*E[q].x + D[q].y*E[q].y + D[q].z*E[q].z + D[q].w*E[q].w;
    }
#pragma unroll
    for (int off = 32; off; off >>= 1) {
        na  += __shfl_xor(na,  off, 64);
        nb  += __shfl_xor(nb,  off, 64);
        nc  += __shfl_xor(nc,  off, 64);
        nd  += __shfl_xor(nd,  off, 64);
        ne  += __shfl_xor(ne,  off, 64);
        dab += __shfl_xor(dab, off, 64);
        dbc += __shfl_xor(dbc, off, 64);
        dcd += __shfl_xor(dcd, off, 64);
        dde += __shfl_xor(dde, off, 64);
    }

    if (lane == 0) {
        float sa = sqrtf(na), sb = sqrtf(nb), sc = sqrtf(nc);
        float sd = sqrtf(nd), se = sqrtf(ne);
        float4 r;
        r.x =      dab / fmaxf(sa * sb, EPSV) / TEMP;
        r.y = v1 ? dbc / fmaxf(sb * sc, EPSV) / TEMP : PADV;
        r.z = v2 ? dcd / fmaxf(sc * sd, EPSV) / TEMP : PADV;
        r.w = v3 ? dde / fmaxf(sd * se, EPSV) / TEMP : PADV;
        *(float4*)(out_cos + b * SS + j0) = r;   // j0 % 4 == 0 -> aligned
    }
}

extern "C" void kernel_launch(void* const* d_in, const int* in_sizes, int n_in,
                              void* d_out, int out_size, void* d_ws, size_t ws_size,
                              hipStream_t stream) {
    const float* seq    = (const float*)d_in[0];   // [B,S,D] f32
    const int*   labels = (const int*)d_in[1];     // [B,S] i32

    float* out_cos = (float*)d_out;                // [B,S]
    float* out_lab = (float*)d_out + BB * SS;      // [B,S] as floats

    int2* desc = (int2*)d_ws;                      // B*S int2 descriptors

    compact_kernel<<<BB, 1024, 0, stream>>>(labels, desc, out_cos, out_lab);

    dim3 grid(SS / 16, BB);                        // 4 waves/block, 4 ranks/wave
    cos_kernel<<<grid, 256, 0, stream>>>(seq, desc, out_cos);
}

// Round 11
// 16.421 us; speedup vs baseline: 1.2008x; 1.2008x over previous
//
#include <hip/hip_runtime.h>

#define BB 8
#define SS 4096
#define DD 1024
#define TEMP 0.1f
#define PADV -100.0f
#define EPSV 1e-8f

// One block (1024 threads) per batch. Scan labels -> compacted positions in
// LDS, write label outputs + all pads for BOTH chunks, then emit pair
// descriptors desc[b][j] = (pos_j, pos_{(j+1)%c}) for j<c, (-1,-1) otherwise.
__global__ __launch_bounds__(1024) void compact_kernel(const int* __restrict__ labels,
                                                       int2* __restrict__ desc,
                                                       float* __restrict__ out_cos,
                                                       float* __restrict__ out_lab) {
    int b = blockIdx.x;
    int t = threadIdx.x;
    int lane = t & 63, wave = t >> 6;

    __shared__ int pos[SS];
    __shared__ int wsum[16];

    int4 v = ((const int4*)(labels + b * SS))[t];
    int vals[4] = {v.x, v.y, v.z, v.w};
    int mycnt = (vals[0] != -100) + (vals[1] != -100) + (vals[2] != -100) + (vals[3] != -100);

    int scan = mycnt;
#pragma unroll
    for (int off = 1; off < 64; off <<= 1) {
        int n = __shfl_up(scan, off, 64);
        if (lane >= off) scan += n;
    }
    if (lane == 63) wsum[wave] = scan;
    __syncthreads();

    int wbase = 0, c = 0;
#pragma unroll
    for (int w = 0; w < 16; ++w) {
        int s = wsum[w];
        wbase += (w < wave) ? s : 0;
        c += s;
    }
    int o = wbase + scan - mycnt;

#pragma unroll
    for (int i = 0; i < 4; ++i) {
        if (vals[i] != -100) {
            pos[o]              = 4 * t + i;
            out_lab[b * SS + o] = (float)vals[i];
            ++o;
        }
    }
#pragma unroll
    for (int i = 0; i < 4; ++i) {
        int s = 4 * t + i;
        if (s >= c) { out_lab[b * SS + s] = PADV; out_cos[b * SS + s] = PADV; }
    }
    __syncthreads();

    int2 d[4];
#pragma unroll
    for (int i = 0; i < 4; ++i) {
        int j = 4 * t + i;
        if (j < c) {
            int jn = (j + 1 == c) ? 0 : (j + 1);
            d[i].x = pos[j];
            d[i].y = pos[jn];
        } else {
            d[i].x = -1;
            d[i].y = -1;
        }
    }
    int4* dp = (int4*)(desc + (size_t)b * SS + 4 * t);
    dp[0] = make_int4(d[0].x, d[0].y, d[1].x, d[1].y);
    dp[1] = make_int4(d[2].x, d[2].y, d[3].x, d[3].y);
}

// One WAVE per 2 consecutive ranks. Single int4 descriptor load (j0 even ->
// 16B aligned, covers both pairs: (i0,i1,i1,i2)), then 3 parallel vector
// loads. Best-measured variant (R6: 16.60 us).
__global__ __launch_bounds__(256) void cos_kernel(const float* __restrict__ x,
                                                  const int2* __restrict__ desc,
                                                  float* __restrict__ out_cos) {
    int b    = blockIdx.y;
    int lane = threadIdx.x & 63;
    int wid  = threadIdx.x >> 6;
    int j0   = (blockIdx.x * 4 + wid) * 2;

    int4 D = *(const int4*)(desc + (size_t)b * SS + j0);
    if (D.x < 0) return;                     // pads already written by compact
    bool p1 = (D.z >= 0);
    int i0 = D.x, i1 = D.y;
    int i2 = p1 ? D.w : D.y;                 // keep pointer valid when !p1

    const float* xb = x + (size_t)b * SS * DD + (size_t)lane * 4;
    const float* pa = xb + (size_t)i0 * DD;
    const float* pb = xb + (size_t)i1 * DD;
    const float* pc = xb + (size_t)i2 * DD;

    float4 A[4], B[4], C[4];
#pragma unroll
    for (int q = 0; q < 4; ++q) {
        A[q] = *(const float4*)(pa + q * 256);
        B[q] = *(const float4*)(pb + q * 256);
        C[q] = *(const float4*)(pc + q * 256);
    }

    float na = 0.f, nb = 0.f, nc = 0.f, dab = 0.f, dbc = 0.f;
#pragma unroll
    for (int q = 0; q < 4; ++q) {
        na  += A[q].x*A[q].x + A[q].y*A[q].y + A[q].z*A[q].z + A[q].w*A[q].w;
        nb  += B[q].x*B[q].x + B[q].y*B[q].y + B[q].z*B[q].z + B[q].w*B[q].w;
        nc  += C[q].x*C[q].x + C[q].y*C[q].y + C[q].z*C[q].z + C[q].w*C[q].w;
        dab += A[q].x*B[q].x + A[q].y*B[q].y + A[q].z*B[q].z + A[q].w*B[q].w;
        dbc += B[q].x*C[q].x + B[q].y*C[q].y + B[q].z*C[q].z + B[q].w*C[q].w;
    }
#pragma unroll
    for (int off = 32; off; off >>= 1) {
        na  += __shfl_xor(na,  off, 64);
        nb  += __shfl_xor(nb,  off, 64);
        nc  += __shfl_xor(nc,  off, 64);
        dab += __shfl_xor(dab, off, 64);
        dbc += __shfl_xor(dbc, off, 64);
    }

    if (lane == 0) {
        float r0 = dab / fmaxf(sqrtf(na) * sqrtf(nb), EPSV) / TEMP;
        float* op = out_cos + b * SS + j0;
        if (p1) {
            float r1 = dbc / fmaxf(sqrtf(nb) * sqrtf(nc), EPSV) / TEMP;
            *(float2*)op = make_float2(r0, r1);
        } else {
            *op = r0;
        }
    }
}

extern "C" void kernel_launch(void* const* d_in, const int* in_sizes, int n_in,
                              void* d_out, int out_size, void* d_ws, size_t ws_size,
                              hipStream_t stream) {
    const float* seq    = (const float*)d_in[0];   // [B,S,D] f32
    const int*   labels = (const int*)d_in[1];     // [B,S] i32

    float* out_cos = (float*)d_out;                // [B,S]
    float* out_lab = (float*)d_out + BB * SS;      // [B,S] as floats

    int2* desc = (int2*)d_ws;                      // B*S int2 descriptors

    compact_kernel<<<BB, 1024, 0, stream>>>(labels, desc, out_cos, out_lab);

    dim3 grid(SS / 8, BB);                         // 4 waves/block, 2 ranks/wave
    cos_kernel<<<grid, 256, 0, stream>>>(seq, desc, out_cos);
}